// Round 5
// baseline (58.689 us; speedup 1.0000x reference)
//
#include <hip/hip_runtime.h>
#include <stdint.h>

typedef __attribute__((ext_vector_type(2))) float f32x2;
typedef __attribute__((ext_vector_type(4))) float f32x4;
typedef __attribute__((ext_vector_type(8))) short bf16x8;

static constexpr int N_ = 4, C_ = 256, HW_ = 4096;
static constexpr int CO_ = 256, KTAP = 9, KK = 2304;  // KK = C_*KTAP
static constexpr int NSTEP = 72;                      // KK / 32
static constexpr int A_STEP_BYTES = 16 * 64 * 16;     // one K-step plane of A: 16KB

static constexpr size_t NHWC_BYTES = (size_t)N_ * HW_ * C_ * 2;  // 8 MB
static constexpr size_t ABF_OFF    = NHWC_BYTES;
static constexpr size_t ABF_BYTES  = (size_t)NSTEP * A_STEP_BYTES;  // 1.18 MB

__device__ inline unsigned f2bf(float f) {
  unsigned u = __builtin_bit_cast(unsigned, f);
  unsigned r = u + 0x7FFFu + ((u >> 16) & 1u);
  return r >> 16;
}
__device__ inline float asf(unsigned u) { return __builtin_bit_cast(float, u); }

// ---------------- NCHW f32 -> NHWC bf16 ----------------
__global__ __launch_bounds__(256) void k_nchw_to_nhwc(const float* __restrict__ in,
                                                      unsigned short* __restrict__ nhwc) {
  __shared__ float tile[64][65];
  int b = blockIdx.x;
  int n = b >> 8, cg = (b >> 6) & 3, hwg = b & 63;
  int c0 = cg * 64, hw0 = hwg * 64;
  int t = threadIdx.x;
  int col = t & 63, r0 = t >> 6;
  const float* src = in + (size_t)(n * C_ + c0) * HW_ + hw0;
#pragma unroll
  for (int i = 0; i < 16; ++i) {
    int row = r0 + i * 4;
    tile[row][col] = src[(size_t)row * HW_ + col];
  }
  __syncthreads();
  int pr = t >> 2, cc0 = (t & 3) * 16;
  unsigned us[8];
#pragma unroll
  for (int i = 0; i < 8; ++i) {
    unsigned lo = f2bf(tile[cc0 + 2 * i][pr]);
    unsigned hi = f2bf(tile[cc0 + 2 * i + 1][pr]);
    us[i] = lo | (hi << 16);
  }
  unsigned* dst = (unsigned*)(nhwc + (size_t)(n * HW_ + hw0 + pr) * C_ + c0 + cc0);
  ((uint4*)dst)[0] = make_uint4(us[0], us[1], us[2], us[3]);
  ((uint4*)dst)[1] = make_uint4(us[4], us[5], us[6], us[7]);
}

// ---------------- filter f32 [O][C][3][3] -> bf16 fragment-major ----------------
// abf2[((s*16 + rb)*64 + lane)*8 + j]  where s = tap*8 + (c>>5), rb = o>>4,
// lane = ((c>>3)&3)*16 + (o&15), j = c&7.
__global__ __launch_bounds__(256) void k_prep_filter(const float* __restrict__ filt,
                                                     unsigned short* __restrict__ abf2) {
  int gid = blockIdx.x * 256 + threadIdx.x;
  int o = gid >> 8, c = gid & 255;
  const float* f = filt + (size_t)(o * C_ + c) * KTAP;
  int rb = o >> 4;
  int lane = ((c >> 3) & 3) * 16 + (o & 15);
  int j = c & 7;
#pragma unroll
  for (int tap = 0; tap < KTAP; ++tap) {
    int s = tap * 8 + (c >> 5);
    abf2[((size_t)(s * 16 + rb) * 64 + lane) * 8 + j] = (unsigned short)f2bf(f[tap]);
  }
}

struct GB { unsigned g[4]; f32x4 w; };

// bilinear combine of 2 channels from 4 corners -> 2 bf16 (4B) into LDS.
// packed f32x2 math (v_pk_fma_f32) + v_cvt_pk_bf16_f32.
__device__ __forceinline__ void buildB2(const unsigned* g, f32x4 w, char* dst) {
  f32x2 a0 = {asf(g[0] << 16), asf(g[0] & 0xffff0000u)};
  f32x2 a1 = {asf(g[1] << 16), asf(g[1] & 0xffff0000u)};
  f32x2 a2 = {asf(g[2] << 16), asf(g[2] & 0xffff0000u)};
  f32x2 a3 = {asf(g[3] << 16), asf(g[3] & 0xffff0000u)};
  f32x2 r = w.x * a0 + w.y * a1 + w.z * a2 + w.w * a3;
  unsigned o;
  asm("v_cvt_pk_bf16_f32 %0, %1, %2" : "=v"(o) : "v"(r.x), "v"(r.y));
  *(unsigned*)dst = o;
}

#define MFMA_BF16 __builtin_amdgcn_mfma_f32_16x16x32_bf16

// One K-step. Consumes B(S) from buf RDP; builds B(S+1) into buf WRP from bank
// GCON; issues gathers g(S+2) into bank GISS; prefetches A(S+1) into AN0/AN1.
#define PIPE(S, GCON, GISS, AC0, AC1, AN0, AN1, RDP, WRP)                         \
  do {                                                                            \
    int s1_ = (S) + 1 < NSTEP ? (S) + 1 : NSTEP - 1;                              \
    int s2_ = (S) + 2 < NSTEP ? (S) + 2 : NSTEP - 1;                              \
    AN0 = *(const bf16x8*)(aoff0 + (size_t)s1_ * A_STEP_BYTES);                   \
    AN1 = *(const bf16x8*)(aoff1 + (size_t)s1_ * A_STEP_BYTES);                   \
    if ((s2_ & 7) == 0) {                                                         \
      int tp_ = s2_ >> 3;                                                         \
      uint4 ra_ = *(const uint4*)&recA[(tp_ * 64 + p_b) * 4];                     \
      wS = *(const f32x4*)&recW[(tp_ * 64 + p_b) * 4];                            \
      vS.x = ra_.x + cg4; vS.y = ra_.y + cg4;                                     \
      vS.z = ra_.z + cg4; vS.w = ra_.w + cg4;                                     \
    }                                                                             \
    {                                                                             \
      unsigned co_ = (unsigned)((s2_ & 7) * 64);                                  \
      GISS.g[0] = *(const unsigned*)(nb_u + vS.x + co_);                          \
      GISS.g[1] = *(const unsigned*)(nb_u + vS.y + co_);                          \
      GISS.g[2] = *(const unsigned*)(nb_u + vS.z + co_);                          \
      GISS.g[3] = *(const unsigned*)(nb_u + vS.w + co_);                          \
      GISS.w = wS;                                                                \
    }                                                                             \
    __builtin_amdgcn_sched_barrier(0);                                            \
    {                                                                             \
      const char* bb_ = (const char*)&Bl[0][0] + (RDP) * 4096;                    \
      bf16x8 b0_ = *(const bf16x8*)(bb_ + bo0);                                   \
      bf16x8 b1_ = *(const bf16x8*)(bb_ + bo1);                                   \
      __builtin_amdgcn_s_setprio(1);                                              \
      acc[0][0] = MFMA_BF16(AC0, b0_, acc[0][0], 0, 0, 0);                        \
      acc[1][0] = MFMA_BF16(AC1, b0_, acc[1][0], 0, 0, 0);                        \
      acc[0][1] = MFMA_BF16(AC0, b1_, acc[0][1], 0, 0, 0);                        \
      acc[1][1] = MFMA_BF16(AC1, b1_, acc[1][1], 0, 0, 0);                        \
      __builtin_amdgcn_s_setprio(0);                                              \
    }                                                                             \
    buildB2(GCON.g, GCON.w, (WRP) ? bw1 : bw0);                                   \
    asm volatile("s_waitcnt lgkmcnt(0)" ::: "memory");                            \
    __builtin_amdgcn_s_barrier();                                                 \
    asm volatile("" ::: "memory");                                                \
  } while (0)

// ---------------- fused sample + GEMM ----------------
// 256 blocks (one per output row) x 1024 threads (16 waves = 8 Cout-groups x 2
// px-groups; wave tile 32 Cout x 32 px -> acc[2][2], 2 A-frags, 2 B-frags).
// B LDS per step-buffer (4KB): addr = c*1024 + (px ^ 4c)*16 + ck*4.
//   reads: 8 consecutive lanes cover 8 bank-quads (conflict-free)
//   writes: px^4c makes k-groups 2-way (free).
__global__ __launch_bounds__(1024, 4) void k_dcn_gemm(const unsigned short* __restrict__ nhwc,
                                                      const unsigned short* __restrict__ abf2,
                                                      const float* __restrict__ offs,
                                                      const float* __restrict__ msk,
                                                      float* __restrict__ out) {
  __shared__ __align__(16) unsigned short Bl[2][2048];  // 2 x 4KB step buffers
  __shared__ float recW[KTAP * 64 * 4];
  __shared__ unsigned recA[KTAP * 64 * 4];

  int bid = blockIdx.x;
  int b = ((bid & 7) << 5) | (bid >> 3);  // XCD-aware swizzle (bijective, 256%8==0)
  int n = b >> 6;
  int ho = b & 63;
  int hw0 = ho << 6;
  int t = threadIdx.x;

  // --- per (pixel, tap) sampling records ---
  for (int r = t; r < 576; r += 1024) {
    int pl = r / 9;
    int tap = r - pl * 9;
    int hw = hw0 + pl;
    float dy = offs[(size_t)(n * 18 + 2 * tap) * HW_ + hw];
    float dx = offs[(size_t)(n * 18 + 2 * tap + 1) * HW_ + hw];
    float mk = msk[(size_t)(n * 9 + tap) * HW_ + hw];
    float y = (float)(ho - 1 + tap / 3) + dy;
    float x = (float)(pl - 1 + tap % 3) + dx;
    float fy = floorf(y), fx = floorf(x);
    float ly = y - fy, lx = x - fx;
    int y0 = (int)fy, x0 = (int)fx;
    int y1 = y0 + 1, x1 = x0 + 1;
    float vy0 = (y0 >= 0 && y0 < 64) ? 1.f : 0.f;
    float vy1 = (y1 >= 0 && y1 < 64) ? 1.f : 0.f;
    float vx0 = (x0 >= 0 && x0 < 64) ? 1.f : 0.f;
    float vx1 = (x1 >= 0 && x1 < 64) ? 1.f : 0.f;
    int y0c = min(max(y0, 0), 63), y1c = min(max(y1, 0), 63);
    int x0c = min(max(x0, 0), 63), x1c = min(max(x1, 0), 63);
    int base = (tap * 64 + pl) * 4;
    recW[base + 0] = (1.f - ly) * (1.f - lx) * mk * vy0 * vx0;
    recW[base + 1] = (1.f - ly) * lx * mk * vy0 * vx1;
    recW[base + 2] = ly * (1.f - lx) * mk * vy1 * vx0;
    recW[base + 3] = ly * lx * mk * vy1 * vx1;
    recA[base + 0] = (unsigned)((y0c * 64 + x0c) * 512);
    recA[base + 1] = (unsigned)((y0c * 64 + x1c) * 512);
    recA[base + 2] = (unsigned)((y1c * 64 + x0c) * 512);
    recA[base + 3] = (unsigned)((y1c * 64 + x1c) * 512);
  }
  __syncthreads();

  int lane = t & 63, wv = t >> 6;
  int ig = wv >> 1;   // Cout group (32 Cout)
  int jg = wv & 1;    // px group (32 px)
  int p_b = t >> 4;   // builder pixel 0..63
  int cg = t & 15;    // builder channel-pair 0..15 (channels 2cg, 2cg+1)
  int cq = cg >> 2, ck = cg & 3;
  unsigned cg4 = (unsigned)(cg * 4);

  const char* aoff0 = (const char*)abf2 + ((ig * 2 + 0) * 64 + lane) * 16;
  const char* aoff1 = (const char*)abf2 + ((ig * 2 + 1) * 64 + lane) * 16;
  const char* nb_u = (const char*)nhwc + (size_t)n * HW_ * C_ * 2;  // uniform base

  int wbyte = cq * 1024 + ((p_b ^ (4 * cq)) * 16) + ck * 4;
  char* bw0 = (char*)&Bl[0][0] + wbyte;
  char* bw1 = bw0 + 4096;

  int c_r = lane >> 4;
  int pxl0 = jg * 32 + (lane & 15);
  const int bo0 = c_r * 1024 + ((pxl0 ^ (4 * c_r)) * 16);
  const int bo1 = c_r * 1024 + (((pxl0 + 16) ^ (4 * c_r)) * 16);

  f32x4 acc[2][2];
#pragma unroll
  for (int mi = 0; mi < 2; ++mi)
#pragma unroll
    for (int ni = 0; ni < 2; ++ni) acc[mi][ni] = (f32x4){0.f, 0.f, 0.f, 0.f};

  GB gA, gB;
  bf16x8 afc0, afc1, afn0, afn1;
  uint4 vS;
  f32x4 wS;

  // --- prologue: gathers g(0)->gA, g(1)->gB, A(0); build B(0) into buf0 ---
  {
    uint4 ra0 = *(const uint4*)&recA[p_b * 4];  // tap 0
    wS = *(const f32x4*)&recW[p_b * 4];
    vS.x = ra0.x + cg4; vS.y = ra0.y + cg4; vS.z = ra0.z + cg4; vS.w = ra0.w + cg4;
    gA.g[0] = *(const unsigned*)(nb_u + vS.x);
    gA.g[1] = *(const unsigned*)(nb_u + vS.y);
    gA.g[2] = *(const unsigned*)(nb_u + vS.z);
    gA.g[3] = *(const unsigned*)(nb_u + vS.w);
    gA.w = wS;
    gB.g[0] = *(const unsigned*)(nb_u + vS.x + 64);
    gB.g[1] = *(const unsigned*)(nb_u + vS.y + 64);
    gB.g[2] = *(const unsigned*)(nb_u + vS.z + 64);
    gB.g[3] = *(const unsigned*)(nb_u + vS.w + 64);
    gB.w = wS;
    afc0 = *(const bf16x8*)(aoff0);
    afc1 = *(const bf16x8*)(aoff1);
    buildB2(gA.g, gA.w, bw0);
    asm volatile("s_waitcnt lgkmcnt(0)" ::: "memory");
    __builtin_amdgcn_s_barrier();
    asm volatile("" ::: "memory");
  }

  // --- main loop: 72 steps, one barrier per step ---
  for (int s = 0; s < NSTEP; s += 2) {
    PIPE(s,     gB, gA, afc0, afc1, afn0, afn1, 0, 1);
    PIPE(s + 1, gA, gB, afn0, afn1, afc0, afc1, 1, 0);
  }

  // --- epilogue: D row = Cout, col = px ---
  float* ob = out + (size_t)n * CO_ * HW_ + hw0 + jg * 32;
#pragma unroll
  for (int mi = 0; mi < 2; ++mi)
#pragma unroll
    for (int ni = 0; ni < 2; ++ni)
#pragma unroll
      for (int jj = 0; jj < 4; ++jj) {
        int o = ig * 32 + mi * 16 + (lane >> 4) * 4 + jj;
        int hw = ni * 16 + (lane & 15);
        ob[(size_t)o * HW_ + hw] = acc[mi][ni][jj];
      }
}

extern "C" void kernel_launch(void* const* d_in, const int* in_sizes, int n_in,
                              void* d_out, int out_size, void* d_ws, size_t ws_size,
                              hipStream_t stream) {
  const float* inp  = (const float*)d_in[0];
  const float* filt = (const float*)d_in[1];
  const float* offs = (const float*)d_in[2];
  const float* msk  = (const float*)d_in[3];
  float* out = (float*)d_out;
  if (ws_size < ABF_OFF + ABF_BYTES) return;  // ~9.6 MB scratch
  unsigned short* nhwc = (unsigned short*)d_ws;
  unsigned short* abf2 = (unsigned short*)((char*)d_ws + ABF_OFF);

  k_nchw_to_nhwc<<<1024, 256, 0, stream>>>(inp, nhwc);
  k_prep_filter<<<256, 256, 0, stream>>>(filt, abf2);
  k_dcn_gemm<<<256, 1024, 0, stream>>>(nhwc, abf2, offs, msk, out);
}

// Round 6
// 53.929 us; speedup vs baseline: 1.0882x; 1.0882x over previous
//
#include <hip/hip_runtime.h>
#include <stdint.h>

typedef __attribute__((ext_vector_type(2))) float f32x2;
typedef __attribute__((ext_vector_type(4))) float f32x4;
typedef __attribute__((ext_vector_type(8))) short bf16x8;

static constexpr int N_ = 4, C_ = 256, HW_ = 4096;
static constexpr int CO_ = 256, KTAP = 9, KK = 2304;  // KK = C_*KTAP
static constexpr int NSTEP = 72;                      // KK / 32
static constexpr int A_STEP_BYTES = 16 * 64 * 16;     // one K-step plane of A: 16KB

static constexpr size_t NHWC_BYTES = (size_t)N_ * HW_ * C_ * 2;  // 8 MB
static constexpr size_t ABF_OFF    = NHWC_BYTES;
static constexpr size_t ABF_BYTES  = (size_t)NSTEP * A_STEP_BYTES;  // 1.18 MB

__device__ inline unsigned f2bf(float f) {
  unsigned u = __builtin_bit_cast(unsigned, f);
  unsigned r = u + 0x7FFFu + ((u >> 16) & 1u);
  return r >> 16;
}
__device__ inline float asf(unsigned u) { return __builtin_bit_cast(float, u); }

// ---------------- NCHW f32 -> NHWC bf16 ----------------
__global__ __launch_bounds__(256) void k_nchw_to_nhwc(const float* __restrict__ in,
                                                      unsigned short* __restrict__ nhwc) {
  __shared__ float tile[64][65];
  int b = blockIdx.x;
  int n = b >> 8, cg = (b >> 6) & 3, hwg = b & 63;
  int c0 = cg * 64, hw0 = hwg * 64;
  int t = threadIdx.x;
  int col = t & 63, r0 = t >> 6;
#pragma unroll
  for (int i = 0; i < 16; ++i) {
    int row = r0 + i * 4;
    tile[row][col] = in[(size_t)(n * C_ + c0 + row) * HW_ + hw0 + col];
  }
  __syncthreads();
  int pr = t >> 2, cc0 = (t & 3) * 16;
  unsigned us[8];
#pragma unroll
  for (int i = 0; i < 8; ++i) {
    unsigned lo = f2bf(tile[cc0 + 2 * i][pr]);
    unsigned hi = f2bf(tile[cc0 + 2 * i + 1][pr]);
    us[i] = lo | (hi << 16);
  }
  unsigned* dst = (unsigned*)(nhwc + (size_t)(n * HW_ + hw0 + pr) * C_ + c0 + cc0);
  ((uint4*)dst)[0] = make_uint4(us[0], us[1], us[2], us[3]);
  ((uint4*)dst)[1] = make_uint4(us[4], us[5], us[6], us[7]);
}

// ---------------- filter f32 [O][C][3][3] -> bf16 fragment-major ----------------
// abf2[((s*16 + rb)*64 + lane)*8 + j]  where s = tap*8 + (c>>5), rb = o>>4,
// lane = ((c>>3)&3)*16 + (o&15), j = c&7.
__global__ __launch_bounds__(256) void k_prep_filter(const float* __restrict__ filt,
                                                     unsigned short* __restrict__ abf2) {
  int gid = blockIdx.x * 256 + threadIdx.x;
  int o = gid >> 8, c = gid & 255;
  const float* f = filt + (size_t)(o * C_ + c) * KTAP;
  int rb = o >> 4;
  int lane = ((c >> 3) & 3) * 16 + (o & 15);
  int j = c & 7;
#pragma unroll
  for (int tap = 0; tap < KTAP; ++tap) {
    int s = tap * 8 + (c >> 5);
    abf2[((size_t)(s * 16 + rb) * 64 + lane) * 8 + j] = (unsigned short)f2bf(f[tap]);
  }
}

struct GB { uint4 g[4]; f32x4 w; };

__device__ __forceinline__ f32x2 unpk(unsigned u) {
  return (f32x2){asf(u << 16), asf(u & 0xffff0000u)};
}

// bilinear combine: 8 channels (4 dwords per corner) -> 8 bf16 (16B) into LDS
__device__ __forceinline__ void buildB8(const GB& b, char* dst) {
  f32x2 r0 = b.w.x * unpk(b.g[0].x) + b.w.y * unpk(b.g[1].x) +
             b.w.z * unpk(b.g[2].x) + b.w.w * unpk(b.g[3].x);
  f32x2 r1 = b.w.x * unpk(b.g[0].y) + b.w.y * unpk(b.g[1].y) +
             b.w.z * unpk(b.g[2].y) + b.w.w * unpk(b.g[3].y);
  f32x2 r2 = b.w.x * unpk(b.g[0].z) + b.w.y * unpk(b.g[1].z) +
             b.w.z * unpk(b.g[2].z) + b.w.w * unpk(b.g[3].z);
  f32x2 r3 = b.w.x * unpk(b.g[0].w) + b.w.y * unpk(b.g[1].w) +
             b.w.z * unpk(b.g[2].w) + b.w.w * unpk(b.g[3].w);
  unsigned o0, o1, o2, o3;
  asm("v_cvt_pk_bf16_f32 %0, %1, %2" : "=v"(o0) : "v"(r0.x), "v"(r0.y));
  asm("v_cvt_pk_bf16_f32 %0, %1, %2" : "=v"(o1) : "v"(r1.x), "v"(r1.y));
  asm("v_cvt_pk_bf16_f32 %0, %1, %2" : "=v"(o2) : "v"(r2.x), "v"(r2.y));
  asm("v_cvt_pk_bf16_f32 %0, %1, %2" : "=v"(o3) : "v"(r3.x), "v"(r3.y));
  *(uint4*)dst = make_uint4(o0, o1, o2, o3);
}

#define MFMA_BF16 __builtin_amdgcn_mfma_f32_16x16x32_bf16

// One K-step, role-split. Consumers (waves 0-7): prefetch A(S+1), read B(S)
// from Bl[RDP], 8 MFMA. Producers (waves 8-11): refresh records if needed,
// issue gathers g(S+2) into GISS, build B(S+1) from GCON into Bl[WRP].
#define PIPE(S, RDP, WRP, GCON, GISS, AC0, AC1, AN0, AN1)                      \
  do {                                                                         \
    if (cons) {                                                                \
      int s1_ = (S) + 1 < NSTEP ? (S) + 1 : NSTEP - 1;                         \
      AN0 = *(const bf16x8*)(aoff0 + (size_t)s1_ * A_STEP_BYTES);              \
      AN1 = *(const bf16x8*)(aoff1 + (size_t)s1_ * A_STEP_BYTES);              \
      const char* bb_ = (const char*)&Bl[0][0] + (RDP) * 4096;                 \
      bf16x8 b0_ = *(const bf16x8*)(bb_ + bo0);                                \
      bf16x8 b1_ = *(const bf16x8*)(bb_ + bo1);                                \
      __builtin_amdgcn_s_setprio(1);                                           \
      acc[0][0] = MFMA_BF16(AC0, b0_, acc[0][0], 0, 0, 0);                     \
      acc[1][0] = MFMA_BF16(AC1, b0_, acc[1][0], 0, 0, 0);                     \
      acc[0][1] = MFMA_BF16(AC0, b1_, acc[0][1], 0, 0, 0);                     \
      acc[1][1] = MFMA_BF16(AC1, b1_, acc[1][1], 0, 0, 0);                     \
      __builtin_amdgcn_s_setprio(0);                                           \
      bf16x8 b2_ = *(const bf16x8*)(bb_ + bo2);                                \
      bf16x8 b3_ = *(const bf16x8*)(bb_ + bo3);                                \
      __builtin_amdgcn_s_setprio(1);                                           \
      acc[0][2] = MFMA_BF16(AC0, b2_, acc[0][2], 0, 0, 0);                     \
      acc[1][2] = MFMA_BF16(AC1, b2_, acc[1][2], 0, 0, 0);                     \
      acc[0][3] = MFMA_BF16(AC0, b3_, acc[0][3], 0, 0, 0);                     \
      acc[1][3] = MFMA_BF16(AC1, b3_, acc[1][3], 0, 0, 0);                     \
      __builtin_amdgcn_s_setprio(0);                                           \
    } else {                                                                   \
      int s2_ = (S) + 2 < NSTEP ? (S) + 2 : NSTEP - 1;                         \
      if ((s2_ & 7) == 0) {                                                    \
        int tp_ = s2_ >> 3;                                                    \
        uint4 ra_ = *(const uint4*)&recA[(tp_ * 64 + p_b) * 4];                \
        wS = *(const f32x4*)&recW[(tp_ * 64 + p_b) * 4];                       \
        vS.x = ra_.x + kq16; vS.y = ra_.y + kq16;                              \
        vS.z = ra_.z + kq16; vS.w = ra_.w + kq16;                              \
      }                                                                        \
      unsigned co_ = (unsigned)((s2_ & 7) * 64);                               \
      GISS.g[0] = *(const uint4*)(nb_u + vS.x + co_);                          \
      GISS.g[1] = *(const uint4*)(nb_u + vS.y + co_);                          \
      GISS.g[2] = *(const uint4*)(nb_u + vS.z + co_);                          \
      GISS.g[3] = *(const uint4*)(nb_u + vS.w + co_);                          \
      GISS.w = wS;                                                             \
      buildB8(GCON, bwp + (WRP) * 4096);                                       \
      asm volatile("s_waitcnt lgkmcnt(0)" ::: "memory");                       \
    }                                                                          \
    asm volatile("" ::: "memory");                                             \
    __builtin_amdgcn_s_barrier();                                              \
    asm volatile("" ::: "memory");                                             \
  } while (0)

// ---------------- fused sample + GEMM (producer/consumer waves) ----------------
// 256 blocks (one per output row) x 768 threads (12 waves, 3/SIMD):
//   waves 0-7  = consumers: wave tile 32 Cout x 64 px (acc[2][4])
//   waves 8-11 = producers: 256 thr = 64 px x 4 ch-groups(8ch), depth-2 gathers
// B LDS per step-buffer (4KB): addr = cq*1024 + ((px + 5*cq)&63)*16  (cq=ch>>3)
//   -> conflict-free for both ds_write_b128 (producers) and ds_read_b128.
__global__ __launch_bounds__(768, 3) void k_dcn_gemm(const unsigned short* __restrict__ nhwc,
                                                     const unsigned short* __restrict__ abf2,
                                                     const float* __restrict__ offs,
                                                     const float* __restrict__ msk,
                                                     float* __restrict__ out) {
  __shared__ __align__(16) unsigned short Bl[2][2048];  // 2 x 4KB step buffers
  __shared__ float recW[KTAP * 64 * 4];
  __shared__ unsigned recA[KTAP * 64 * 4];

  int bid = blockIdx.x;
  int b = ((bid & 7) << 5) | (bid >> 3);  // XCD-aware swizzle (bijective, 256%8==0)
  int n = b >> 6;
  int ho = b & 63;
  int hw0 = ho << 6;
  int t = threadIdx.x;

  // --- per (pixel, tap) sampling records ---
  for (int r = t; r < 576; r += 768) {
    int pl = r / 9;
    int tap = r - pl * 9;
    int hw = hw0 + pl;
    float dy = offs[(size_t)(n * 18 + 2 * tap) * HW_ + hw];
    float dx = offs[(size_t)(n * 18 + 2 * tap + 1) * HW_ + hw];
    float mk = msk[(size_t)(n * 9 + tap) * HW_ + hw];
    float y = (float)(ho - 1 + tap / 3) + dy;
    float x = (float)(pl - 1 + tap % 3) + dx;
    float fy = floorf(y), fx = floorf(x);
    float ly = y - fy, lx = x - fx;
    int y0 = (int)fy, x0 = (int)fx;
    int y1 = y0 + 1, x1 = x0 + 1;
    float vy0 = (y0 >= 0 && y0 < 64) ? 1.f : 0.f;
    float vy1 = (y1 >= 0 && y1 < 64) ? 1.f : 0.f;
    float vx0 = (x0 >= 0 && x0 < 64) ? 1.f : 0.f;
    float vx1 = (x1 >= 0 && x1 < 64) ? 1.f : 0.f;
    int y0c = min(max(y0, 0), 63), y1c = min(max(y1, 0), 63);
    int x0c = min(max(x0, 0), 63), x1c = min(max(x1, 0), 63);
    int base = (tap * 64 + pl) * 4;
    recW[base + 0] = (1.f - ly) * (1.f - lx) * mk * vy0 * vx0;
    recW[base + 1] = (1.f - ly) * lx * mk * vy0 * vx1;
    recW[base + 2] = ly * (1.f - lx) * mk * vy1 * vx0;
    recW[base + 3] = ly * lx * mk * vy1 * vx1;
    recA[base + 0] = (unsigned)((y0c * 64 + x0c) * 512);
    recA[base + 1] = (unsigned)((y0c * 64 + x1c) * 512);
    recA[base + 2] = (unsigned)((y1c * 64 + x0c) * 512);
    recA[base + 3] = (unsigned)((y1c * 64 + x1c) * 512);
  }
  __syncthreads();

  int lane = t & 63, wv = t >> 6;
  bool cons = wv < 8;

  // consumer addressing
  const char* aoff0 = (const char*)abf2 + ((wv * 2 + 0) * 64 + lane) * 16;
  const char* aoff1 = aoff0 + 1024;
  int cqr = lane >> 4;
  int pxl = lane & 15;
  const int bo0 = cqr * 1024 + ((((0 * 16 + pxl) + cqr * 5) & 63) * 16);
  const int bo1 = cqr * 1024 + ((((1 * 16 + pxl) + cqr * 5) & 63) * 16);
  const int bo2 = cqr * 1024 + ((((2 * 16 + pxl) + cqr * 5) & 63) * 16);
  const int bo3 = cqr * 1024 + ((((3 * 16 + pxl) + cqr * 5) & 63) * 16);

  // producer addressing (threads 512..767): 4 thr/px, 8 ch each
  int p_b = (t >> 2) & 63;
  int kq = t & 3;
  unsigned kq16 = (unsigned)(kq * 16);
  const char* nb_u = (const char*)nhwc + (size_t)n * HW_ * C_ * 2;
  char* bwp = (char*)&Bl[0][0] + (kq * 1024 + ((p_b + kq * 5) & 63) * 16);

  f32x4 acc[2][4];
#pragma unroll
  for (int mi = 0; mi < 2; ++mi)
#pragma unroll
    for (int ni = 0; ni < 4; ++ni) acc[mi][ni] = (f32x4){0.f, 0.f, 0.f, 0.f};

  GB gA, gB;
  bf16x8 afc0, afc1, afn0, afn1;
  uint4 vS;
  f32x4 wS;

  // --- prologue ---
  if (cons) {
    afc0 = *(const bf16x8*)(aoff0);
    afc1 = *(const bf16x8*)(aoff1);
  } else {
    uint4 ra0 = *(const uint4*)&recA[p_b * 4];  // tap 0
    wS = *(const f32x4*)&recW[p_b * 4];
    vS.x = ra0.x + kq16; vS.y = ra0.y + kq16;
    vS.z = ra0.z + kq16; vS.w = ra0.w + kq16;
    gA.g[0] = *(const uint4*)(nb_u + vS.x);
    gA.g[1] = *(const uint4*)(nb_u + vS.y);
    gA.g[2] = *(const uint4*)(nb_u + vS.z);
    gA.g[3] = *(const uint4*)(nb_u + vS.w);
    gA.w = wS;
    gB.g[0] = *(const uint4*)(nb_u + vS.x + 64);
    gB.g[1] = *(const uint4*)(nb_u + vS.y + 64);
    gB.g[2] = *(const uint4*)(nb_u + vS.z + 64);
    gB.g[3] = *(const uint4*)(nb_u + vS.w + 64);
    gB.w = wS;
    buildB8(gA, bwp);  // B(0) into buf0
    asm volatile("s_waitcnt lgkmcnt(0)" ::: "memory");
  }
  asm volatile("" ::: "memory");
  __builtin_amdgcn_s_barrier();
  asm volatile("" ::: "memory");

  // --- main loop: 72 steps, one barrier per step ---
  for (int s = 0; s < NSTEP; s += 2) {
    PIPE(s,     0, 1, gB, gA, afc0, afc1, afn0, afn1);
    PIPE(s + 1, 1, 0, gA, gB, afn0, afn1, afc0, afc1);
  }

  // --- epilogue (consumers only): D row = Cout, col = px ---
  if (cons) {
    float* ob = out + (size_t)n * CO_ * HW_ + hw0;
#pragma unroll
    for (int mi = 0; mi < 2; ++mi)
#pragma unroll
      for (int ni = 0; ni < 4; ++ni)
#pragma unroll
        for (int jj = 0; jj < 4; ++jj) {
          int o = wv * 32 + mi * 16 + (lane >> 4) * 4 + jj;
          int hw = ni * 16 + (lane & 15);
          ob[(size_t)o * HW_ + hw] = acc[mi][ni][jj];
        }
  }
}

extern "C" void kernel_launch(void* const* d_in, const int* in_sizes, int n_in,
                              void* d_out, int out_size, void* d_ws, size_t ws_size,
                              hipStream_t stream) {
  const float* inp  = (const float*)d_in[0];
  const float* filt = (const float*)d_in[1];
  const float* offs = (const float*)d_in[2];
  const float* msk  = (const float*)d_in[3];
  float* out = (float*)d_out;
  if (ws_size < ABF_OFF + ABF_BYTES) return;  // ~9.6 MB scratch
  unsigned short* nhwc = (unsigned short*)d_ws;
  unsigned short* abf2 = (unsigned short*)((char*)d_ws + ABF_OFF);

  k_nchw_to_nhwc<<<1024, 256, 0, stream>>>(inp, nhwc);
  k_prep_filter<<<256, 256, 0, stream>>>(filt, abf2);
  k_dcn_gemm<<<256, 768, 0, stream>>>(nhwc, abf2, offs, msk, out);
}